// Round 1
// baseline (88.068 us; speedup 1.0000x reference)
//
#include <hip/hip_runtime.h>

// Problem constants (fixed in the reference): B=32, N=20000, E=1e6, R=100, T=20.
#define T_VAL 20
#define RT_VAL 2000   // R*T key space

// Dispatch 1: plain store-based zero of the output (replaces the previous
// atomicMax(ptr,0) zero-init — 640k independent L2 RMW transactions — with
// ~2.56 MB of coalesced int4 stores, ~1 us). Stream order guarantees it
// completes before the edge pass scatters.
__global__ void zero_out(int4* __restrict__ out4, int* __restrict__ out,
                         int BN4, int BN) {
    int i = blockIdx.x * blockDim.x + threadIdx.x;
    if (i < BN4) out4[i] = make_int4(0, 0, 0, 0);
    // scalar tail for BN not divisible by 4
    if (i == 0) {
        for (int j = BN4 * 4; j < BN; ++j) out[j] = 0;
    }
}

// Dispatch 2: edge pass.
//  - builds the (rel,ts) -> batch-bitmask table in LDS (8 KB) per block
//  - streams edges 4/thread via int4 loads of rel/ts; matched edges (~1.6%)
//    scatter-max via int atomicMax (float bits are non-negative since
//    w,h in [0,1), so int max == float max, and baseline 0 gives the
//    clamp(min=0) + empty-row semantics for free).
__global__ void edge_pass(const int4* __restrict__ rel4,
                          const int4* __restrict__ ts4,
                          const int* __restrict__ head,
                          const int* __restrict__ tail,
                          const float* __restrict__ w,
                          const float* __restrict__ h,
                          const int* __restrict__ r_index,
                          const int* __restrict__ timestamp,
                          int* __restrict__ out_i,
                          int E4, int E, int N, int B) {
    __shared__ unsigned smask[RT_VAL];
    for (int i = threadIdx.x; i < RT_VAL; i += blockDim.x) smask[i] = 0u;
    __syncthreads();
    if (threadIdx.x < (unsigned)B && threadIdx.x < 32) {
        int b = threadIdx.x;
        atomicOr(&smask[r_index[b] * T_VAL + timestamp[b]], 1u << b);
    }
    __syncthreads();

    int i4 = blockIdx.x * blockDim.x + threadIdx.x;
    if (i4 < E4) {
        int4 r = rel4[i4];
        int4 t = ts4[i4];
        int rr[4] = {r.x, r.y, r.z, r.w};
        int tt[4] = {t.x, t.y, t.z, t.w};
        int base = i4 * 4;
#pragma unroll
        for (int j = 0; j < 4; ++j) {
            unsigned m = smask[rr[j] * T_VAL + tt[j]];
            if (m) {
                int e = base + j;
                float we = w[e];
                int hd = head[e];
                int tl = tail[e];
                while (m) {
                    int b = __ffs(m) - 1;
                    m &= m - 1;
                    float val = h[b * N + hd] * we;
                    atomicMax(out_i + (size_t)b * N + tl, __float_as_int(val));
                }
            }
        }
    }

    // Scalar tail for E not divisible by 4 (E=1e6 is, but stay robust).
    if (blockIdx.x == 0 && threadIdx.x == 0) {
        for (int e = E4 * 4; e < E; ++e) {
            unsigned m = smask[((const int*)rel4)[e] * T_VAL + ((const int*)ts4)[e]];
            if (m) {
                float we = w[e];
                int hd = head[e];
                int tl = tail[e];
                while (m) {
                    int b = __ffs(m) - 1;
                    m &= m - 1;
                    float val = h[b * N + hd] * we;
                    atomicMax(out_i + (size_t)b * N + tl, __float_as_int(val));
                }
            }
        }
    }
}

extern "C" void kernel_launch(void* const* d_in, const int* in_sizes, int n_in,
                              void* d_out, int out_size, void* d_ws, size_t ws_size,
                              hipStream_t stream) {
    const float* h_prob    = (const float*)d_in[0];
    const float* edge_w    = (const float*)d_in[1];
    const int*   edge_head = (const int*)d_in[2];
    const int*   edge_tail = (const int*)d_in[3];
    const int*   edge_rel  = (const int*)d_in[4];
    const int*   edge_ts   = (const int*)d_in[5];
    const int*   r_index   = (const int*)d_in[6];
    const int*   timestamp = (const int*)d_in[7];

    int B = in_sizes[6];
    int E = in_sizes[1];
    int N = in_sizes[0] / B;
    int BN = out_size;

    // Dispatch 1: zero output with coalesced stores.
    int BN4 = BN / 4;
    int zblocks = (BN4 + 255) / 256;
    if (zblocks < 1) zblocks = 1;
    zero_out<<<zblocks, 256, 0, stream>>>((int4*)d_out, (int*)d_out, BN4, BN);

    // Dispatch 2: edge pass (stream-ordered after the zero).
    int E4 = E / 4;
    int blocks = (E4 + 255) / 256;
    edge_pass<<<blocks, 256, 0, stream>>>(
        (const int4*)edge_rel, (const int4*)edge_ts,
        edge_head, edge_tail, edge_w, h_prob,
        r_index, timestamp, (int*)d_out, E4, E, N, B);
}